// Round 8
// baseline (43.779 us; speedup 1.0000x reference)
//
#include <hip/hip_runtime.h>
#include <math.h>

// Rodrigues rotation: R rotates unit(vec1) onto unit(vec2), per (B,N) element.
// B*N = 2,097,152 elements; in: 2 x (elem,3) f32, out: (elem,3,3) f32.
//
// R7: wave-autonomous staging — R2's exact access patterns, ZERO barriers.
//   Each wave owns a private 576-float4 (9 KB) LDS slice. One 256-element
//   tile per wave (64 lanes x 4 elems). Phases within the wave:
//     1. coop load: 3 linear f4 passes per input into slice (1024 B/instr)
//     2. lane reads its 4 elems: 3x ds_read_b128 stride-3-f4 per input
//        (compiler inserts lgkmcnt waits -- same-slice dependence)
//     3. compute 4 rotation matrices (approx rcp/rsq; wave-uniform rare-path)
//     4. lane writes 9x ds_write_b128 at stride-9-f4 (aliases dead input)
//     5. coop store: 9 linear f4 passes (full 128B lines, through L2)
//   No __syncthreads anywhere -> no vmcnt(0)-drain (the m97 barrier stall),
//   waves desynchronize -> continuous read/write mix instead of convoys.

#define TPB 256
#define WAVES 4                    // per block
#define ELEMS_PER_WAVE 256         // 64 lanes x 4 elems
#define IN_F4 192                  // per input per wave: 256*3/4
#define OUT_F4 576                 // per wave: 256*9/4

__device__ __forceinline__ void rot_main(const float* __restrict__ va,
                                         const float* __restrict__ vb,
                                         float* __restrict__ R,
                                         float* __restrict__ s2o,
                                         float* __restrict__ co)
{
    const float v1x = va[0], v1y = va[1], v1z = va[2];
    const float v2x = vb[0], v2y = vb[1], v2z = vb[2];
    const float rn1 = __builtin_amdgcn_rsqf(v1x * v1x + v1y * v1y + v1z * v1z);
    const float rn2 = __builtin_amdgcn_rsqf(v2x * v2x + v2y * v2y + v2z * v2z);
    const float ax = v1x * rn1, ay = v1y * rn1, az = v1z * rn1;
    const float bx = v2x * rn2, by = v2y * rn2, bz = v2z * rn2;

    const float vx = ay * bz - az * by;
    const float vy = az * bx - ax * bz;
    const float vz = ax * by - ay * bx;
    const float c  = ax * bx + ay * by + az * bz;
    const float s2 = vx * vx + vy * vy + vz * vz;

    // s < 1e-30 (f64 in ref)  <=>  s2 == 0 in f32
    const bool s_zero = (s2 == 0.0f);
    const float f = (1.0f - c) * (s_zero ? 1.0f : __builtin_amdgcn_rcpf(s2));

    // R = I + K + (v v^T - s2 I) * f   (K^2 == v v^T - |v|^2 I exactly)
    R[0] = 1.0f + (vx * vx - s2) * f;
    R[1] = -vz  + (vx * vy) * f;
    R[2] =  vy  + (vx * vz) * f;
    R[3] =  vz  + (vy * vx) * f;
    R[4] = 1.0f + (vy * vy - s2) * f;
    R[5] = -vx  + (vy * vz) * f;
    R[6] = -vy  + (vz * vx) * f;
    R[7] =  vx  + (vz * vy) * f;
    R[8] = 1.0f + (vz * vz - s2) * f;

    *s2o = s2;
    *co  = c;
}

// Rare-path fixup: identity / 180-degree cases. Wave-uniform-guarded by caller.
__device__ __noinline__ void rot_fixup(const float* __restrict__ va,
                                       float s2, float c, float* __restrict__ R)
{
    if (s2 != 0.0f) return;

    const float v1x = va[0], v1y = va[1], v1z = va[2];
    const float rn1 = __builtin_amdgcn_rsqf(v1x * v1x + v1y * v1y + v1z * v1z);
    const float ax = v1x * rn1, ay = v1y * rn1, az = v1z * rn1;

    const bool close = (fabsf(ax - 1.0f) <= (1e-8f + 1e-5f)) &&
                       (fabsf(ay) <= 1e-8f) &&
                       (fabsf(az) <= 1e-8f);
    const float exv = close ? 0.0f : 1.0f;   // axis = close ? e2 : e1
    const float eyv = close ? 1.0f : 0.0f;
    float px = -az * eyv;
    float py =  az * exv;
    float pz =  ax * eyv - ay * exv;
    const float pq0 = px * px + py * py + pz * pz;
    const float rpn = (pq0 == 0.0f) ? 1.0f : __builtin_amdgcn_rsqf(pq0);
    px *= rpn; py *= rpn; pz *= rpn;
    const float pq = px * px + py * py + pz * pz;

    if (c > 0.0f) {
        R[0] = 1.0f; R[1] = 0.0f; R[2] = 0.0f;
        R[3] = 0.0f; R[4] = 1.0f; R[5] = 0.0f;
        R[6] = 0.0f; R[7] = 0.0f; R[8] = 1.0f;
    } else if (c < 0.0f) {
        R[0] = 1.0f + 2.0f * (px * px - pq);
        R[1] = 2.0f * (px * py);
        R[2] = 2.0f * (px * pz);
        R[3] = R[1];
        R[4] = 1.0f + 2.0f * (py * py - pq);
        R[5] = 2.0f * (py * pz);
        R[6] = R[2];
        R[7] = R[5];
        R[8] = 1.0f + 2.0f * (pz * pz - pq);
    }
}

__global__ __launch_bounds__(TPB, 4)
void rodrigues_wave(const float4* __restrict__ v1,
                    const float4* __restrict__ v2,
                    float4* __restrict__ out4, long ntiles)
{
    __shared__ float4 lds[WAVES * OUT_F4];        // 36 KB

    const int tid  = threadIdx.x;
    const int wave = tid >> 6;
    const int lane = tid & 63;
    float4* S = lds + wave * OUT_F4;              // this wave's private slice

    const long tile = (long)blockIdx.x * WAVES + wave;
    if (tile >= ntiles) return;

    // ---- 1. coop load: linear f4, A at S[0..191], B at S[192..383] ----
    const float4* ga = v1 + tile * IN_F4;
    const float4* gb = v2 + tile * IN_F4;
#pragma unroll
    for (int p = 0; p < 3; ++p) {
        S[p * 64 + lane]          = ga[p * 64 + lane];
        S[IN_F4 + p * 64 + lane]  = gb[p * 64 + lane];
    }

    // ---- 2. lane's 4 elements: 3x ds_read_b128 stride-3-f4 per input ----
    // (compiler inserts lgkmcnt waits: same-slice memory dependence)
    const float4 A0 = S[3 * lane + 0], A1 = S[3 * lane + 1], A2 = S[3 * lane + 2];
    const float4 B0 = S[IN_F4 + 3 * lane + 0],
                 B1 = S[IN_F4 + 3 * lane + 1],
                 B2 = S[IN_F4 + 3 * lane + 2];

    const float va[12] = {A0.x, A0.y, A0.z, A0.w, A1.x, A1.y, A1.z, A1.w,
                          A2.x, A2.y, A2.z, A2.w};
    const float vb[12] = {B0.x, B0.y, B0.z, B0.w, B1.x, B1.y, B1.z, B1.w,
                          B2.x, B2.y, B2.z, B2.w};

    // ---- 3. compute ----
    float R[36], s2e[4], ce[4];
#pragma unroll
    for (int e = 0; e < 4; ++e)
        rot_main(&va[3 * e], &vb[3 * e], &R[9 * e], &s2e[e], &ce[e]);

    const bool any_spec = (s2e[0] == 0.0f) | (s2e[1] == 0.0f) |
                          (s2e[2] == 0.0f) | (s2e[3] == 0.0f);
    if (__any(any_spec)) {
#pragma unroll
        for (int e = 0; e < 4; ++e)
            rot_fixup(&va[3 * e], s2e[e], ce[e], &R[9 * e]);
    }

    // ---- 4. lane -> slice: 9x ds_write_b128 stride-9-f4 (input now dead;
    //         all lanes' reads precede these writes in wave program order) ----
#pragma unroll
    for (int k = 0; k < 9; ++k)
        S[9 * lane + k] = make_float4(R[4 * k + 0], R[4 * k + 1],
                                      R[4 * k + 2], R[4 * k + 3]);

    // ---- 5. coop store: 9 linear f4 passes, full 128B lines ----
    float4* go = out4 + tile * OUT_F4;
#pragma unroll
    for (int p = 0; p < 9; ++p)
        go[p * 64 + lane] = S[p * 64 + lane];
}

// Scalar tail for n % ELEMS_PER_WAVE leftovers (not launched for this shape).
__global__ __launch_bounds__(64)
void rodrigues1_kernel(const float* __restrict__ v1,
                       const float* __restrict__ v2,
                       float* __restrict__ out, int start, int n)
{
    const int i = start + blockIdx.x * blockDim.x + threadIdx.x;
    if (i >= n) return;
    float R[9], s2, c;
    float a3[3] = {v1[3 * i + 0], v1[3 * i + 1], v1[3 * i + 2]};
    float b3[3] = {v2[3 * i + 0], v2[3 * i + 1], v2[3 * i + 2]};
    rot_main(a3, b3, R, &s2, &c);
    rot_fixup(a3, s2, c, R);
#pragma unroll
    for (int k = 0; k < 9; ++k) out[9 * i + k] = R[k];
}

extern "C" void kernel_launch(void* const* d_in, const int* in_sizes, int n_in,
                              void* d_out, int out_size, void* d_ws, size_t ws_size,
                              hipStream_t stream)
{
    const float* v1 = (const float*)d_in[0];
    const float* v2 = (const float*)d_in[1];
    const int n = in_sizes[0] / 3;               // B*N elements (2,097,152)

    const long ntiles = n / ELEMS_PER_WAVE;      // 8192 wave-tiles
    if (ntiles > 0) {
        const int grid = (int)((ntiles + WAVES - 1) / WAVES);
        rodrigues_wave<<<grid, TPB, 0, stream>>>(
            (const float4*)v1, (const float4*)v2, (float4*)d_out, ntiles);
    }
    const int rem = n - (int)(ntiles * ELEMS_PER_WAVE);
    if (rem > 0) {
        rodrigues1_kernel<<<(rem + 63) / 64, 64, 0, stream>>>(
            v1, v2, (float*)d_out, (int)(ntiles * ELEMS_PER_WAVE), n);
    }
}

// Round 9
// 24.531 us; speedup vs baseline: 1.7847x; 1.7847x over previous
//
#include <hip/hip_runtime.h>
#include <math.h>

// Rodrigues rotation: R rotates unit(vec1) onto unit(vec2), per (B,N) element.
// B*N = 2,097,152 elements; in: 2 x (elem,3) f32, out: (elem,3,3) f32.
// Memory-bound: ~126 MB total traffic -> floor ~20 us @ 6.3 TB/s copy ceiling.
//
// FINAL (= R2, best of 6 structures tested):
//   global->LDS: 3x float4 passes per input (1024 B/wave-instr)
//   LDS->reg:    3x ds_read_b128 per input (stride-3-f4: 8 lanes cover all
//                32 banks -> minimum aliasing, throughput-conflict-free)
//   reg->LDS:    9x ds_write_b128 at stride 9 f4 (same minimal bank pattern)
//   LDS->global: 9x linear coalesced float4 store passes
// LDS aliased (inputs dead after reg read): max(24,36) = 36 KB -> 4 blocks/CU.
//
// Measured 24.64 us = 97% of per-direction HBM write rate (75.5 MB / 24.6 us
// = 3.07 TB/s vs 3.15 TB/s/direction implied by the 6.29 TB/s copy ceiling).
// Structures that regressed: gather/1-thread-per-out-f4 (32 us), direct loads
// + single barrier TPB=128 (44 us), wave-private-slice zero-barrier (44 us),
// nontemporal stores (2.3x WRITE_SIZE amplification, 44 us).

#define TPB 256
#define EPT 4
#define EPB (TPB * EPT)          // 1024 elements per block

__device__ __forceinline__ void rot_one(float v1x, float v1y, float v1z,
                                        float v2x, float v2y, float v2z,
                                        float* __restrict__ R /* 9 floats */)
{
    const float rn1 = __builtin_amdgcn_rsqf(v1x * v1x + v1y * v1y + v1z * v1z);
    const float rn2 = __builtin_amdgcn_rsqf(v2x * v2x + v2y * v2y + v2z * v2z);
    const float ax = v1x * rn1, ay = v1y * rn1, az = v1z * rn1;
    const float bx = v2x * rn2, by = v2y * rn2, bz = v2z * rn2;

    // v = cross(a,b), c = dot(a,b), s2 = |v|^2
    const float vx = ay * bz - az * by;
    const float vy = az * bx - ax * bz;
    const float vz = ax * by - ay * bx;
    const float c  = ax * bx + ay * by + az * bz;
    const float s2 = vx * vx + vy * vy + vz * vz;

    // s < 1e-30  <=>  s2 == 0 in f32
    const bool s_zero = (s2 == 0.0f);
    const float f = (1.0f - c) * (s_zero ? 1.0f : __builtin_amdgcn_rcpf(s2));

    // R = I + K + (v v^T - s2 I) * f   (K^2 == v v^T - |v|^2 I exactly)
    const float r00 = 1.0f + (vx * vx - s2) * f;
    const float r01 = -vz  + (vx * vy) * f;
    const float r02 =  vy  + (vx * vz) * f;
    const float r10 =  vz  + (vy * vx) * f;
    const float r11 = 1.0f + (vy * vy - s2) * f;
    const float r12 = -vx  + (vy * vz) * f;
    const float r20 = -vy  + (vz * vx) * f;
    const float r21 =  vx  + (vz * vy) * f;
    const float r22 = 1.0f + (vz * vz - s2) * f;

    // 180-degree (antiparallel) branch, branchless.
    const bool close = (fabsf(ax - 1.0f) <= (1e-8f + 1e-5f)) &&
                       (fabsf(ay) <= 1e-8f) &&
                       (fabsf(az) <= 1e-8f);
    const float exv = close ? 0.0f : 1.0f;   // axis = close ? e2 : e1
    const float eyv = close ? 1.0f : 0.0f;
    float px = -az * eyv;
    float py =  az * exv;
    float pz =  ax * eyv - ay * exv;
    const float pq0 = px * px + py * py + pz * pz;
    const float rpn = (pq0 == 0.0f) ? 1.0f : __builtin_amdgcn_rsqf(pq0);
    px *= rpn; py *= rpn; pz *= rpn;
    const float pq = px * px + py * py + pz * pz;
    const float q00 = 1.0f + 2.0f * (px * px - pq);
    const float q01 = 2.0f * (px * py);
    const float q02 = 2.0f * (px * pz);
    const float q11 = 1.0f + 2.0f * (py * py - pq);
    const float q12 = 2.0f * (py * pz);
    const float q22 = 1.0f + 2.0f * (pz * pz - pq);

    const bool id_case  = s_zero && (c > 0.0f);
    const bool neg_case = s_zero && (c < 0.0f);

    R[0] = id_case ? 1.0f : (neg_case ? q00 : r00);
    R[1] = id_case ? 0.0f : (neg_case ? q01 : r01);
    R[2] = id_case ? 0.0f : (neg_case ? q02 : r02);
    R[3] = id_case ? 0.0f : (neg_case ? q01 : r10);
    R[4] = id_case ? 1.0f : (neg_case ? q11 : r11);
    R[5] = id_case ? 0.0f : (neg_case ? q12 : r12);
    R[6] = id_case ? 0.0f : (neg_case ? q02 : r20);
    R[7] = id_case ? 0.0f : (neg_case ? q12 : r21);
    R[8] = id_case ? 1.0f : (neg_case ? q22 : r22);
}

// Full blocks only: 1024 elements per block, everything b128-wide.
__global__ __launch_bounds__(TPB, 4)
void rodrigues4_staged(const float4* __restrict__ v1,
                       const float4* __restrict__ v2,
                       float4* __restrict__ out)
{
    __shared__ float4 lds[9 * EPB / 4];          // 2304 f4 = 36 KB (aliased)
    float4* in_a = lds;                          // [0..767]
    float4* in_b = lds + (3 * EPB / 4);          // [768..1535]

    const int tid = threadIdx.x;
    const long bi = blockIdx.x;

    // ---- global -> LDS, fully coalesced float4 ----
    const float4* ga = v1 + bi * (3 * EPB / 4);
    const float4* gb = v2 + bi * (3 * EPB / 4);
#pragma unroll
    for (int p = 0; p < 3; ++p) {
        in_a[p * TPB + tid] = ga[p * TPB + tid];
        in_b[p * TPB + tid] = gb[p * TPB + tid];
    }
    __syncthreads();

    // ---- LDS -> regs: 3x ds_read_b128 per input ----
    const float4 A0 = in_a[3 * tid + 0], A1 = in_a[3 * tid + 1], A2 = in_a[3 * tid + 2];
    const float4 B0 = in_b[3 * tid + 0], B1 = in_b[3 * tid + 1], B2 = in_b[3 * tid + 2];
    __syncthreads();                             // inputs dead; reuse LDS for out

    const float va[12] = {A0.x, A0.y, A0.z, A0.w, A1.x, A1.y, A1.z, A1.w,
                          A2.x, A2.y, A2.z, A2.w};
    const float vb[12] = {B0.x, B0.y, B0.z, B0.w, B1.x, B1.y, B1.z, B1.w,
                          B2.x, B2.y, B2.z, B2.w};

    float R[36];
#pragma unroll
    for (int e = 0; e < 4; ++e)
        rot_one(va[3 * e + 0], va[3 * e + 1], va[3 * e + 2],
                vb[3 * e + 0], vb[3 * e + 1], vb[3 * e + 2], &R[9 * e]);

    // ---- regs -> LDS: 9x ds_write_b128 at stride 9 f4 ----
#pragma unroll
    for (int k = 0; k < 9; ++k)
        lds[9 * tid + k] = make_float4(R[4 * k + 0], R[4 * k + 1],
                                       R[4 * k + 2], R[4 * k + 3]);
    __syncthreads();

    // ---- LDS -> global: 9 linear coalesced float4 passes ----
    float4* go = out + bi * (9 * EPB / 4);
#pragma unroll
    for (int p = 0; p < 9; ++p)
        go[p * TPB + tid] = lds[p * TPB + tid];
}

// Scalar tail for n % EPB leftovers (not launched for this shape).
__global__ __launch_bounds__(64)
void rodrigues1_kernel(const float* __restrict__ v1,
                       const float* __restrict__ v2,
                       float* __restrict__ out, int start, int n)
{
    const int i = start + blockIdx.x * blockDim.x + threadIdx.x;
    if (i >= n) return;
    float R[9];
    rot_one(v1[3 * i + 0], v1[3 * i + 1], v1[3 * i + 2],
            v2[3 * i + 0], v2[3 * i + 1], v2[3 * i + 2], R);
#pragma unroll
    for (int k = 0; k < 9; ++k) out[9 * i + k] = R[k];
}

extern "C" void kernel_launch(void* const* d_in, const int* in_sizes, int n_in,
                              void* d_out, int out_size, void* d_ws, size_t ws_size,
                              hipStream_t stream)
{
    const float* v1 = (const float*)d_in[0];
    const float* v2 = (const float*)d_in[1];
    const int n = in_sizes[0] / 3;               // B*N elements (2,097,152)

    const int nfull = n / EPB;                   // full 1024-element blocks
    if (nfull > 0) {
        rodrigues4_staged<<<nfull, TPB, 0, stream>>>(
            (const float4*)v1, (const float4*)v2, (float4*)d_out);
    }
    const int rem = n - nfull * EPB;
    if (rem > 0) {
        rodrigues1_kernel<<<(rem + 63) / 64, 64, 0, stream>>>(
            v1, v2, (float*)d_out, nfull * EPB, n);
    }
}